// Round 1
// baseline (9090.607 us; speedup 1.0000x reference)
//
#include <hip/hip_runtime.h>
#include <hip/hip_bf16.h>
#include <cstdint>
#include <cstddef>

#define N_NODES 50000
#define F_DIM   128
#define E_EDGES 800000
#define BN_EPS  1e-5f

typedef __attribute__((ext_vector_type(8))) short short8;
typedef __attribute__((ext_vector_type(4))) float f32x4;
typedef unsigned short ushort_t;

__device__ __forceinline__ ushort_t f2b(float f) {
    union { float f; uint32_t u; } v; v.f = f;
    uint32_t u = v.u + 0x7fffu + ((v.u >> 16) & 1u);  // round-to-nearest-even
    return (ushort_t)(u >> 16);
}

// ---------------------------------------------------------------- prep: f32 -> bf16 weights
__global__ __launch_bounds__(256) void prep_kernel(
    const float* __restrict__ Wa1, const float* __restrict__ W0, const float* __restrict__ W1,
    ushort_t* __restrict__ Wa1b, ushort_t* __restrict__ W0b, ushort_t* __restrict__ W1b)
{
    int i = blockIdx.x * 256 + threadIdx.x;
    if (i < 3 * 16384) Wa1b[i] = f2b(Wa1[i]);
    if (i < 16384) { W0b[i] = f2b(W0[i]); W1b[i] = f2b(W1[i]); }
}

// ---------------------------------------------------------------- edge MLP -> sigmoid weight + deg
// wave tile: 16 edges (M) x 128 hidden (N), K=F=128 via 4x mfma_16x16x32_bf16 per 16-col block
__global__ __launch_bounds__(256) void edge_mlp_kernel(
    const float* __restrict__ x,
    const int* __restrict__ ei0, const int* __restrict__ ei1, const int* __restrict__ ei2,
    const ushort_t* __restrict__ Wa1b, const float* __restrict__ ba1,
    const float* __restrict__ Wa2, const float* __restrict__ ba2,
    float* __restrict__ ew, float* __restrict__ deg)
{
    const int s = blockIdx.y;
    const int* ei = (s == 0) ? ei0 : ((s == 1) ? ei1 : ei2);
    const ushort_t* W = Wa1b + s * 16384;
    const float* b1v = ba1 + s * 128;
    const float* w2v = Wa2 + s * 128;
    const float b2 = ba2[s];
    float* ews  = ew  + (size_t)s * E_EDGES;
    float* degs = deg + (size_t)s * N_NODES;

    const int wave = threadIdx.x >> 6;
    const int lane = threadIdx.x & 63;
    const int quad = lane >> 4;
    const int lcol = lane & 15;
    const int e0 = (blockIdx.x * 4 + wave) * 16;
    if (e0 >= E_EDGES) return;
    const int e = e0 + lcol;
    const int rn = ei[e];
    const int cn = ei[E_EDGES + e];

    // A fragments: adif[e0+lcol][kb*32 + quad*8 + j]
    short8 a[4];
    const float* xr = x + (size_t)rn * 128;
    const float* xc = x + (size_t)cn * 128;
#pragma unroll
    for (int kb = 0; kb < 4; kb++) {
        const int k0 = kb * 32 + quad * 8;
        float4 r0 = *(const float4*)(xr + k0);
        float4 r1 = *(const float4*)(xr + k0 + 4);
        float4 c0 = *(const float4*)(xc + k0);
        float4 c1 = *(const float4*)(xc + k0 + 4);
        short8 t;
        t[0] = (short)f2b(fabsf(r0.x - c0.x));
        t[1] = (short)f2b(fabsf(r0.y - c0.y));
        t[2] = (short)f2b(fabsf(r0.z - c0.z));
        t[3] = (short)f2b(fabsf(r0.w - c0.w));
        t[4] = (short)f2b(fabsf(r1.x - c1.x));
        t[5] = (short)f2b(fabsf(r1.y - c1.y));
        t[6] = (short)f2b(fabsf(r1.z - c1.z));
        t[7] = (short)f2b(fabsf(r1.w - c1.w));
        a[kb] = t;
    }

    float acc[4] = {0.f, 0.f, 0.f, 0.f};
#pragma unroll
    for (int nb = 0; nb < 8; nb++) {
        f32x4 d = {0.f, 0.f, 0.f, 0.f};
        const int h = nb * 16 + lcol;
        const ushort_t* wp = W + h * 128 + quad * 8;
#pragma unroll
        for (int kb = 0; kb < 4; kb++) {
            short8 b = *(const short8*)(wp + kb * 32);
            d = __builtin_amdgcn_mfma_f32_16x16x32_bf16(a[kb], b, d, 0, 0, 0);
        }
        const float bias = b1v[h];
        const float wv = w2v[h];
#pragma unroll
        for (int r = 0; r < 4; r++) {
            float v = d[r] + bias;       // hid[e0+quad*4+r][h]
            v = v > 0.f ? v : 0.f;
            acc[r] += v * wv;
        }
    }
    // reduce across the 16 lanes of the quad (masks < 16 stay in-quad)
#pragma unroll
    for (int r = 0; r < 4; r++) {
#pragma unroll
        for (int m = 1; m < 16; m <<= 1) acc[r] += __shfl_xor(acc[r], m, 64);
    }
    if (lcol < 4) {
        float sv = (lcol == 0) ? acc[0] : ((lcol == 1) ? acc[1] : ((lcol == 2) ? acc[2] : acc[3]));
        float w = 1.f / (1.f + __expf(-(sv + b2)));
        const int ee = e0 + quad * 4 + lcol;
        ews[ee] = w;
        const int cc = ei[E_EDGES + ee];
        unsafeAtomicAdd(&degs[cc], w);
    }
}

// ---------------------------------------------------------------- dinv = deg>0 ? rsqrt(max(deg,1e-30)) : 0
__global__ __launch_bounds__(256) void dinv_kernel(const float* __restrict__ deg,
                                                   float* __restrict__ dinv, int n)
{
    int i = blockIdx.x * 256 + threadIdx.x;
    if (i < n) {
        float d = deg[i];
        dinv[i] = d > 0.f ? rsqrtf(fmaxf(d, 1e-30f)) : 0.f;
    }
}

// ---------------------------------------------------------------- dense rows GEMM: out[i][h] = sum_f A[i][f]*W[h][f]
__global__ __launch_bounds__(256) void gemm_rows_kernel(
    const float* __restrict__ A, const ushort_t* __restrict__ Wb,
    float* __restrict__ out, int n)
{
    const int wave = threadIdx.x >> 6;
    const int lane = threadIdx.x & 63;
    const int quad = lane >> 4;
    const int lcol = lane & 15;
    const int i0 = (blockIdx.x * 4 + wave) * 16;
    if (i0 >= n) return;

    short8 a[4];
    const float* ar = A + (size_t)(i0 + lcol) * 128;
#pragma unroll
    for (int kb = 0; kb < 4; kb++) {
        const int k0 = kb * 32 + quad * 8;
        float4 r0 = *(const float4*)(ar + k0);
        float4 r1 = *(const float4*)(ar + k0 + 4);
        short8 t;
        t[0] = (short)f2b(r0.x); t[1] = (short)f2b(r0.y);
        t[2] = (short)f2b(r0.z); t[3] = (short)f2b(r0.w);
        t[4] = (short)f2b(r1.x); t[5] = (short)f2b(r1.y);
        t[6] = (short)f2b(r1.z); t[7] = (short)f2b(r1.w);
        a[kb] = t;
    }

#pragma unroll
    for (int nb = 0; nb < 8; nb++) {
        f32x4 d = {0.f, 0.f, 0.f, 0.f};
        const ushort_t* wp = Wb + (nb * 16 + lcol) * 128 + quad * 8;
#pragma unroll
        for (int kb = 0; kb < 4; kb++) {
            short8 b = *(const short8*)(wp + kb * 32);
            d = __builtin_amdgcn_mfma_f32_16x16x32_bf16(a[kb], b, d, 0, 0, 0);
        }
#pragma unroll
        for (int r = 0; r < 4; r++) {
            out[(size_t)(i0 + quad * 4 + r) * 128 + nb * 16 + lcol] = d[r];
        }
    }
}

// ---------------------------------------------------------------- scatter: agg[col] += dinv[row]*ew*dinv[col] * h[row][:]
__global__ __launch_bounds__(256) void scatter_kernel(
    const float* __restrict__ h,
    const int* __restrict__ ei0, const int* __restrict__ ei1, const int* __restrict__ ei2,
    const float* __restrict__ ew, const float* __restrict__ dinv,
    float* __restrict__ agg)
{
    const int s = blockIdx.y;
    const int* ei = (s == 0) ? ei0 : ((s == 1) ? ei1 : ei2);
    const float* ews = ew + (size_t)s * E_EDGES;
    const float* ds  = dinv + (size_t)s * N_NODES;

    const long e = (long)blockIdx.x * 8 + (threadIdx.x >> 5);
    if (e >= E_EDGES) return;
    const int t = threadIdx.x & 31;
    const int rn = ei[e];
    const int cn = ei[E_EDGES + e];
    const float w = ds[rn] * ews[e] * ds[cn];

    float4 v = *(const float4*)(h + (size_t)rn * 128 + t * 4);
    float* dst = agg + (size_t)cn * 128 + t * 4;
    unsafeAtomicAdd(dst + 0, w * v.x);
    unsafeAtomicAdd(dst + 1, w * v.y);
    unsafeAtomicAdd(dst + 2, w * v.z);
    unsafeAtomicAdd(dst + 3, w * v.w);
}

// ---------------------------------------------------------------- v = relu(agg + 3*b); accumulate per-feature sum/sumsq
__global__ __launch_bounds__(256) void relu_stats_kernel(
    const float* __restrict__ agg, const float* __restrict__ bias,
    float* __restrict__ v, float* __restrict__ sums)
{
    __shared__ float ls[256], ls2[256];
    float s = 0.f, s2 = 0.f;
    const long total = (long)N_NODES * 128;
    const long stride = (long)gridDim.x * 256;
    for (long i = (long)blockIdx.x * 256 + threadIdx.x; i < total; i += stride) {
        float val = agg[i] + 3.f * bias[(int)(i & 127)];
        val = val > 0.f ? val : 0.f;
        v[i] = val;
        s += val; s2 += val * val;
    }
    ls[threadIdx.x] = s; ls2[threadIdx.x] = s2;
    __syncthreads();
    if (threadIdx.x < 128) {
        s  = ls[threadIdx.x] + ls[threadIdx.x + 128];
        s2 = ls2[threadIdx.x] + ls2[threadIdx.x + 128];
        unsafeAtomicAdd(&sums[threadIdx.x], s);
        unsafeAtomicAdd(&sums[128 + threadIdx.x], s2);
    }
}

__global__ void finalize_stats_kernel(const float* __restrict__ sums,
                                      float* __restrict__ mu, float* __restrict__ rstd)
{
    int f = threadIdx.x;
    float m = sums[f] / (float)N_NODES;
    float var = sums[128 + f] / (float)N_NODES - m * m;
    mu[f] = m;
    rstd[f] = rsqrtf(var + BN_EPS);
}

// ---------------------------------------------------------------- mode 0: out = relu(bn(v));  mode 1: out = bn(v) + xres
__global__ __launch_bounds__(256) void bn_apply_kernel(
    const float* __restrict__ v, const float* __restrict__ mu, const float* __restrict__ rstd,
    const float* __restrict__ gamma, const float* __restrict__ beta,
    const float* __restrict__ xres, float* __restrict__ out, int mode)
{
    const long total = (long)N_NODES * 128;
    const long stride = (long)gridDim.x * 256;
    for (long i = (long)blockIdx.x * 256 + threadIdx.x; i < total; i += stride) {
        const int f = (int)(i & 127);
        float val = (v[i] - mu[f]) * rstd[f] * gamma[f] + beta[f];
        if (mode == 0) val = val > 0.f ? val : 0.f;
        else val += xres[i];
        out[i] = val;
    }
}

// ----------------------------------------------------------------
extern "C" void kernel_launch(void* const* d_in, const int* in_sizes, int n_in,
                              void* d_out, int out_size, void* d_ws, size_t ws_size,
                              hipStream_t stream)
{
    const float* x   = (const float*)d_in[0];
    const int* ei0   = (const int*)d_in[1];
    const int* ei1   = (const int*)d_in[2];
    const int* ei2   = (const int*)d_in[3];
    const float* Wa1 = (const float*)d_in[4];
    const float* ba1 = (const float*)d_in[5];
    const float* Wa2 = (const float*)d_in[6];
    const float* ba2 = (const float*)d_in[7];
    const float* W0  = (const float*)d_in[8];
    const float* b0  = (const float*)d_in[9];
    const float* W1  = (const float*)d_in[10];
    const float* b1  = (const float*)d_in[11];
    const float* g0  = (const float*)d_in[12];
    const float* be0 = (const float*)d_in[13];
    const float* g1  = (const float*)d_in[14];
    const float* be1 = (const float*)d_in[15];
    float* out = (float*)d_out;

    char* ws = (char*)d_ws;
    size_t off = 0;
    auto alloc = [&](size_t bytes) -> void* {
        void* p = ws + off;
        off += (bytes + 255) & ~(size_t)255;
        return p;
    };
    ushort_t* Wa1b = (ushort_t*)alloc(3 * 16384 * 2);
    ushort_t* W0b  = (ushort_t*)alloc(16384 * 2);
    ushort_t* W1b  = (ushort_t*)alloc(16384 * 2);
    float* ew   = (float*)alloc(3ull * E_EDGES * 4);
    float* deg  = (float*)alloc(3ull * N_NODES * 4);
    float* dinv = (float*)alloc(3ull * N_NODES * 4);
    float* hpre = (float*)alloc((size_t)N_NODES * 128 * 4);
    float* agg  = (float*)alloc((size_t)N_NODES * 128 * 4);
    float* hbuf = (float*)alloc((size_t)N_NODES * 128 * 4);
    float* sums0 = (float*)alloc(256 * 4);
    float* sums1 = (float*)alloc(256 * 4);
    float* mu0 = (float*)alloc(128 * 4);
    float* rs0 = (float*)alloc(128 * 4);
    float* mu1 = (float*)alloc(128 * 4);
    float* rs1 = (float*)alloc(128 * 4);
    (void)ws_size; (void)in_sizes; (void)n_in; (void)out_size;

    hipMemsetAsync(deg, 0, 3ull * N_NODES * 4, stream);
    hipMemsetAsync(agg, 0, (size_t)N_NODES * 128 * 4, stream);
    hipMemsetAsync(sums0, 0, 256 * 4, stream);
    hipMemsetAsync(sums1, 0, 256 * 4, stream);

    prep_kernel<<<192, 256, 0, stream>>>(Wa1, W0, W1, Wa1b, W0b, W1b);

    // edge MLP: 12500 blocks x 4 waves x 16 edges = 800000 edges, 3 sets
    edge_mlp_kernel<<<dim3(12500, 3), 256, 0, stream>>>(x, ei0, ei1, ei2, Wa1b, ba1, Wa2, ba2, ew, deg);
    dinv_kernel<<<(3 * N_NODES + 255) / 256, 256, 0, stream>>>(deg, dinv, 3 * N_NODES);

    // layer 0
    gemm_rows_kernel<<<782, 256, 0, stream>>>(x, W0b, hpre, N_NODES);
    scatter_kernel<<<dim3(100000, 3), 256, 0, stream>>>(hpre, ei0, ei1, ei2, ew, dinv, agg);
    relu_stats_kernel<<<512, 256, 0, stream>>>(agg, b0, hbuf, sums0);
    finalize_stats_kernel<<<1, 128, 0, stream>>>(sums0, mu0, rs0);
    bn_apply_kernel<<<512, 256, 0, stream>>>(hbuf, mu0, rs0, g0, be0, nullptr, hpre, 0);

    // layer 1 (reuse agg after re-zero; ordering is stream-serialized)
    hipMemsetAsync(agg, 0, (size_t)N_NODES * 128 * 4, stream);
    gemm_rows_kernel<<<782, 256, 0, stream>>>(hpre, W1b, hbuf, N_NODES);
    scatter_kernel<<<dim3(100000, 3), 256, 0, stream>>>(hbuf, ei0, ei1, ei2, ew, dinv, agg);
    relu_stats_kernel<<<512, 256, 0, stream>>>(agg, b1, hpre, sums1);
    finalize_stats_kernel<<<1, 128, 0, stream>>>(sums1, mu1, rs1);
    bn_apply_kernel<<<512, 256, 0, stream>>>(hpre, mu1, rs1, g1, be1, x, out, 1);
}

// Round 2
// 1619.904 us; speedup vs baseline: 5.6118x; 5.6118x over previous
//
#include <hip/hip_runtime.h>
#include <hip/hip_bf16.h>
#include <cstdint>
#include <cstddef>

#define N_NODES 50000
#define F_DIM   128
#define E_EDGES 800000
#define NNZ     (3 * E_EDGES)
#define BN_EPS  1e-5f

typedef __attribute__((ext_vector_type(8))) short short8;
typedef __attribute__((ext_vector_type(4))) float f32x4;
typedef unsigned short ushort_t;

__device__ __forceinline__ ushort_t f2b(float f) {
    union { float f; uint32_t u; } v; v.f = f;
    uint32_t u = v.u + 0x7fffu + ((v.u >> 16) & 1u);  // round-to-nearest-even
    return (ushort_t)(u >> 16);
}

// ---------------------------------------------------------------- prep: f32 -> bf16 weights
__global__ __launch_bounds__(256) void prep_kernel(
    const float* __restrict__ Wa1, const float* __restrict__ W0, const float* __restrict__ W1,
    ushort_t* __restrict__ Wa1b, ushort_t* __restrict__ W0b, ushort_t* __restrict__ W1b)
{
    int i = blockIdx.x * 256 + threadIdx.x;
    if (i < 3 * 16384) Wa1b[i] = f2b(Wa1[i]);
    if (i < 16384) { W0b[i] = f2b(W0[i]); W1b[i] = f2b(W1[i]); }
}

// ---------------------------------------------------------------- edge MLP -> sigmoid weight + deg
// wave tile: 16 edges (M) x 128 hidden (N), K=F=128 via 4x mfma_16x16x32_bf16 per 16-col block
__global__ __launch_bounds__(256) void edge_mlp_kernel(
    const float* __restrict__ x,
    const int* __restrict__ ei0, const int* __restrict__ ei1, const int* __restrict__ ei2,
    const ushort_t* __restrict__ Wa1b, const float* __restrict__ ba1,
    const float* __restrict__ Wa2, const float* __restrict__ ba2,
    float* __restrict__ ew, float* __restrict__ deg)
{
    const int s = blockIdx.y;
    const int* ei = (s == 0) ? ei0 : ((s == 1) ? ei1 : ei2);
    const ushort_t* W = Wa1b + s * 16384;
    const float* b1v = ba1 + s * 128;
    const float* w2v = Wa2 + s * 128;
    const float b2 = ba2[s];
    float* ews  = ew  + (size_t)s * E_EDGES;
    float* degs = deg + (size_t)s * N_NODES;

    const int wave = threadIdx.x >> 6;
    const int lane = threadIdx.x & 63;
    const int quad = lane >> 4;
    const int lcol = lane & 15;
    const int e0 = (blockIdx.x * 4 + wave) * 16;
    if (e0 >= E_EDGES) return;
    const int e = e0 + lcol;
    const int rn = ei[e];
    const int cn = ei[E_EDGES + e];

    // A fragments: adif[e0+lcol][kb*32 + quad*8 + j]
    short8 a[4];
    const float* xr = x + (size_t)rn * 128;
    const float* xc = x + (size_t)cn * 128;
#pragma unroll
    for (int kb = 0; kb < 4; kb++) {
        const int k0 = kb * 32 + quad * 8;
        float4 r0 = *(const float4*)(xr + k0);
        float4 r1 = *(const float4*)(xr + k0 + 4);
        float4 c0 = *(const float4*)(xc + k0);
        float4 c1 = *(const float4*)(xc + k0 + 4);
        short8 t;
        t[0] = (short)f2b(fabsf(r0.x - c0.x));
        t[1] = (short)f2b(fabsf(r0.y - c0.y));
        t[2] = (short)f2b(fabsf(r0.z - c0.z));
        t[3] = (short)f2b(fabsf(r0.w - c0.w));
        t[4] = (short)f2b(fabsf(r1.x - c1.x));
        t[5] = (short)f2b(fabsf(r1.y - c1.y));
        t[6] = (short)f2b(fabsf(r1.z - c1.z));
        t[7] = (short)f2b(fabsf(r1.w - c1.w));
        a[kb] = t;
    }

    float acc[4] = {0.f, 0.f, 0.f, 0.f};
#pragma unroll
    for (int nb = 0; nb < 8; nb++) {
        f32x4 d = {0.f, 0.f, 0.f, 0.f};
        const int h = nb * 16 + lcol;
        const ushort_t* wp = W + h * 128 + quad * 8;
#pragma unroll
        for (int kb = 0; kb < 4; kb++) {
            short8 b = *(const short8*)(wp + kb * 32);
            d = __builtin_amdgcn_mfma_f32_16x16x32_bf16(a[kb], b, d, 0, 0, 0);
        }
        const float bias = b1v[h];
        const float wv = w2v[h];
#pragma unroll
        for (int r = 0; r < 4; r++) {
            float v = d[r] + bias;       // hid[e0+quad*4+r][h]
            v = v > 0.f ? v : 0.f;
            acc[r] += v * wv;
        }
    }
    // reduce across the 16 lanes of the quad (masks < 16 stay in-quad)
#pragma unroll
    for (int r = 0; r < 4; r++) {
#pragma unroll
        for (int m = 1; m < 16; m <<= 1) acc[r] += __shfl_xor(acc[r], m, 64);
    }
    if (lcol < 4) {
        float sv = (lcol == 0) ? acc[0] : ((lcol == 1) ? acc[1] : ((lcol == 2) ? acc[2] : acc[3]));
        float w = 1.f / (1.f + __expf(-(sv + b2)));
        const int ee = e0 + quad * 4 + lcol;
        ews[ee] = w;
        const int cc = ei[E_EDGES + ee];
        unsafeAtomicAdd(&degs[cc], w);
    }
}

// ---------------------------------------------------------------- dinv = deg>0 ? rsqrt(max(deg,1e-30)) : 0
__global__ __launch_bounds__(256) void dinv_kernel(const float* __restrict__ deg,
                                                   float* __restrict__ dinv, int n)
{
    int i = blockIdx.x * 256 + threadIdx.x;
    if (i < n) {
        float d = deg[i];
        dinv[i] = d > 0.f ? rsqrtf(fmaxf(d, 1e-30f)) : 0.f;
    }
}

// ---------------------------------------------------------------- CSR build: histogram of destination (col) over all 3 sets
__global__ __launch_bounds__(256) void hist_kernel(
    const int* __restrict__ ei0, const int* __restrict__ ei1, const int* __restrict__ ei2,
    int* __restrict__ cnt)
{
    const int s = blockIdx.y;
    const int* ei = (s == 0) ? ei0 : ((s == 1) ? ei1 : ei2);
    int e = blockIdx.x * 256 + threadIdx.x;
    if (e < E_EDGES) atomicAdd(&cnt[ei[E_EDGES + e]], 1);
}

// per-block exclusive scan of 1024 elements + block sums
__global__ __launch_bounds__(1024) void scan1_kernel(
    const int* __restrict__ cnt, int* __restrict__ offs, int* __restrict__ bsum)
{
    __shared__ int ls[1024];
    const int tid = threadIdx.x;
    const int i = blockIdx.x * 1024 + tid;
    int v = (i < N_NODES) ? cnt[i] : 0;
    ls[tid] = v;
    __syncthreads();
#pragma unroll
    for (int d = 1; d < 1024; d <<= 1) {
        int t = (tid >= d) ? ls[tid - d] : 0;
        __syncthreads();
        ls[tid] += t;
        __syncthreads();
    }
    int incl = ls[tid];
    if (i < N_NODES) offs[i] = incl - v;  // block-local exclusive
    if (tid == 1023) bsum[blockIdx.x] = incl;
}

__global__ void scan2_kernel(int* __restrict__ bsum, int* __restrict__ offs, int nb)
{
    if (threadIdx.x == 0) {
        int run = 0;
        for (int b = 0; b < nb; b++) { int t = bsum[b]; bsum[b] = run; run += t; }
        offs[N_NODES] = run;  // == NNZ
    }
}

__global__ __launch_bounds__(1024) void scan3_kernel(
    int* __restrict__ offs, const int* __restrict__ bsum, int* __restrict__ cursor)
{
    const int i = blockIdx.x * 1024 + threadIdx.x;
    if (i < N_NODES) {
        int o = offs[i] + bsum[blockIdx.x];
        offs[i] = o;
        cursor[i] = o;
    }
}

// fill CSR slots: packed (src, wnorm) records, combined over the 3 edge sets
__global__ __launch_bounds__(256) void fill_kernel(
    const int* __restrict__ ei0, const int* __restrict__ ei1, const int* __restrict__ ei2,
    const float* __restrict__ ew, const float* __restrict__ dinv,
    int* __restrict__ cursor, int2* __restrict__ edges)
{
    const int s = blockIdx.y;
    const int* ei = (s == 0) ? ei0 : ((s == 1) ? ei1 : ei2);
    const float* ews = ew + (size_t)s * E_EDGES;
    const float* ds  = dinv + (size_t)s * N_NODES;
    int e = blockIdx.x * 256 + threadIdx.x;
    if (e >= E_EDGES) return;
    const int rn = ei[e];
    const int cn = ei[E_EDGES + e];
    const float w = ds[rn] * ews[e] * ds[cn];
    int pos = atomicAdd(&cursor[cn], 1);
    edges[pos] = make_int2(rn, __float_as_int(w));
}

// ---------------------------------------------------------------- gather-SpMM: v[n] = relu(sum_e w_e * h[src_e] + 3*bias)
// one wave per destination node; lane l owns features 2l, 2l+1
__global__ __launch_bounds__(256) void gather_spmm_kernel(
    const float* __restrict__ h, const int* __restrict__ offs,
    const int2* __restrict__ edges, const float* __restrict__ bias,
    float* __restrict__ vout)
{
    const int wave = threadIdx.x >> 6;
    const int lane = threadIdx.x & 63;
    const int node = blockIdx.x * 4 + wave;
    if (node >= N_NODES) return;
    const int start = offs[node];
    const int end   = offs[node + 1];
    const int f = lane * 2;

    float ax = 0.f, ay = 0.f;
    int e = start;
    for (; e + 2 <= end; e += 2) {
        int2 ev0 = edges[e];
        int2 ev1 = edges[e + 1];
        float w0 = __int_as_float(ev0.y);
        float w1 = __int_as_float(ev1.y);
        float2 h0 = *(const float2*)(h + (size_t)ev0.x * 128 + f);
        float2 h1 = *(const float2*)(h + (size_t)ev1.x * 128 + f);
        ax += w0 * h0.x; ay += w0 * h0.y;
        ax += w1 * h1.x; ay += w1 * h1.y;
    }
    if (e < end) {
        int2 ev = edges[e];
        float w = __int_as_float(ev.y);
        float2 hv = *(const float2*)(h + (size_t)ev.x * 128 + f);
        ax += w * hv.x; ay += w * hv.y;
    }
    float bx = bias[f], by = bias[f + 1];
    ax += 3.f * bx; ay += 3.f * by;
    ax = ax > 0.f ? ax : 0.f;
    ay = ay > 0.f ? ay : 0.f;
    *(float2*)(vout + (size_t)node * 128 + f) = make_float2(ax, ay);
}

// ---------------------------------------------------------------- dense rows GEMM: out[i][h] = sum_f A[i][f]*W[h][f]
__global__ __launch_bounds__(256) void gemm_rows_kernel(
    const float* __restrict__ A, const ushort_t* __restrict__ Wb,
    float* __restrict__ out, int n)
{
    const int wave = threadIdx.x >> 6;
    const int lane = threadIdx.x & 63;
    const int quad = lane >> 4;
    const int lcol = lane & 15;
    const int i0 = (blockIdx.x * 4 + wave) * 16;
    if (i0 >= n) return;

    short8 a[4];
    const float* ar = A + (size_t)(i0 + lcol) * 128;
#pragma unroll
    for (int kb = 0; kb < 4; kb++) {
        const int k0 = kb * 32 + quad * 8;
        float4 r0 = *(const float4*)(ar + k0);
        float4 r1 = *(const float4*)(ar + k0 + 4);
        short8 t;
        t[0] = (short)f2b(r0.x); t[1] = (short)f2b(r0.y);
        t[2] = (short)f2b(r0.z); t[3] = (short)f2b(r0.w);
        t[4] = (short)f2b(r1.x); t[5] = (short)f2b(r1.y);
        t[6] = (short)f2b(r1.z); t[7] = (short)f2b(r1.w);
        a[kb] = t;
    }

#pragma unroll
    for (int nb = 0; nb < 8; nb++) {
        f32x4 d = {0.f, 0.f, 0.f, 0.f};
        const ushort_t* wp = Wb + (nb * 16 + lcol) * 128 + quad * 8;
#pragma unroll
        for (int kb = 0; kb < 4; kb++) {
            short8 b = *(const short8*)(wp + kb * 32);
            d = __builtin_amdgcn_mfma_f32_16x16x32_bf16(a[kb], b, d, 0, 0, 0);
        }
#pragma unroll
        for (int r = 0; r < 4; r++) {
            out[(size_t)(i0 + quad * 4 + r) * 128 + nb * 16 + lcol] = d[r];
        }
    }
}

// ---------------------------------------------------------------- per-feature sum/sumsq of v (already relu'd)
__global__ __launch_bounds__(256) void stats_kernel(
    const float* __restrict__ v, float* __restrict__ sums)
{
    __shared__ float ls[256], ls2[256];
    float s = 0.f, s2 = 0.f;
    const long total = (long)N_NODES * 128;
    const long stride = (long)gridDim.x * 256;
    for (long i = (long)blockIdx.x * 256 + threadIdx.x; i < total; i += stride) {
        float val = v[i];
        s += val; s2 += val * val;
    }
    ls[threadIdx.x] = s; ls2[threadIdx.x] = s2;
    __syncthreads();
    if (threadIdx.x < 128) {
        s  = ls[threadIdx.x] + ls[threadIdx.x + 128];
        s2 = ls2[threadIdx.x] + ls2[threadIdx.x + 128];
        unsafeAtomicAdd(&sums[threadIdx.x], s);
        unsafeAtomicAdd(&sums[128 + threadIdx.x], s2);
    }
}

__global__ void finalize_stats_kernel(const float* __restrict__ sums,
                                      float* __restrict__ mu, float* __restrict__ rstd)
{
    int f = threadIdx.x;
    float m = sums[f] / (float)N_NODES;
    float var = sums[128 + f] / (float)N_NODES - m * m;
    mu[f] = m;
    rstd[f] = rsqrtf(var + BN_EPS);
}

// ---------------------------------------------------------------- mode 0: out = relu(bn(v));  mode 1: out = bn(v) + xres
__global__ __launch_bounds__(256) void bn_apply_kernel(
    const float* __restrict__ v, const float* __restrict__ mu, const float* __restrict__ rstd,
    const float* __restrict__ gamma, const float* __restrict__ beta,
    const float* __restrict__ xres, float* __restrict__ out, int mode)
{
    const long total = (long)N_NODES * 128;
    const long stride = (long)gridDim.x * 256;
    for (long i = (long)blockIdx.x * 256 + threadIdx.x; i < total; i += stride) {
        const int f = (int)(i & 127);
        float val = (v[i] - mu[f]) * rstd[f] * gamma[f] + beta[f];
        if (mode == 0) val = val > 0.f ? val : 0.f;
        else val += xres[i];
        out[i] = val;
    }
}

// ----------------------------------------------------------------
extern "C" void kernel_launch(void* const* d_in, const int* in_sizes, int n_in,
                              void* d_out, int out_size, void* d_ws, size_t ws_size,
                              hipStream_t stream)
{
    const float* x   = (const float*)d_in[0];
    const int* ei0   = (const int*)d_in[1];
    const int* ei1   = (const int*)d_in[2];
    const int* ei2   = (const int*)d_in[3];
    const float* Wa1 = (const float*)d_in[4];
    const float* ba1 = (const float*)d_in[5];
    const float* Wa2 = (const float*)d_in[6];
    const float* ba2 = (const float*)d_in[7];
    const float* W0  = (const float*)d_in[8];
    const float* b0  = (const float*)d_in[9];
    const float* W1  = (const float*)d_in[10];
    const float* b1  = (const float*)d_in[11];
    const float* g0  = (const float*)d_in[12];
    const float* be0 = (const float*)d_in[13];
    const float* g1  = (const float*)d_in[14];
    const float* be1 = (const float*)d_in[15];
    float* out = (float*)d_out;

    char* ws = (char*)d_ws;
    size_t off = 0;
    auto alloc = [&](size_t bytes) -> void* {
        void* p = ws + off;
        off += (bytes + 255) & ~(size_t)255;
        return p;
    };
    ushort_t* Wa1b = (ushort_t*)alloc(3 * 16384 * 2);
    ushort_t* W0b  = (ushort_t*)alloc(16384 * 2);
    ushort_t* W1b  = (ushort_t*)alloc(16384 * 2);
    float* ew    = (float*)alloc(3ull * E_EDGES * 4);
    float* deg   = (float*)alloc(3ull * N_NODES * 4);
    float* dinv  = (float*)alloc(3ull * N_NODES * 4);
    int*   cnt   = (int*)alloc((size_t)N_NODES * 4);
    int*   offs  = (int*)alloc(((size_t)N_NODES + 1) * 4);
    int*   cursor= (int*)alloc((size_t)N_NODES * 4);
    int*   bsum  = (int*)alloc(64 * 4);
    int2*  edges = (int2*)alloc((size_t)NNZ * 8);
    float* hpre  = (float*)alloc((size_t)N_NODES * 128 * 4);
    float* hbuf  = (float*)alloc((size_t)N_NODES * 128 * 4);
    float* sums0 = (float*)alloc(256 * 4);
    float* sums1 = (float*)alloc(256 * 4);
    float* mu0 = (float*)alloc(128 * 4);
    float* rs0 = (float*)alloc(128 * 4);
    float* mu1 = (float*)alloc(128 * 4);
    float* rs1 = (float*)alloc(128 * 4);
    (void)ws_size; (void)in_sizes; (void)n_in; (void)out_size;

    hipMemsetAsync(deg, 0, 3ull * N_NODES * 4, stream);
    hipMemsetAsync(cnt, 0, (size_t)N_NODES * 4, stream);
    hipMemsetAsync(sums0, 0, 256 * 4, stream);
    hipMemsetAsync(sums1, 0, 256 * 4, stream);

    prep_kernel<<<192, 256, 0, stream>>>(Wa1, W0, W1, Wa1b, W0b, W1b);

    // edge weights + degrees
    edge_mlp_kernel<<<dim3(12500, 3), 256, 0, stream>>>(x, ei0, ei1, ei2, Wa1b, ba1, Wa2, ba2, ew, deg);
    dinv_kernel<<<(3 * N_NODES + 255) / 256, 256, 0, stream>>>(deg, dinv, 3 * N_NODES);

    // build combined CSR (by destination) once; reused by both layers
    const int nscan = (N_NODES + 1023) / 1024;  // 49
    hist_kernel<<<dim3(3125, 3), 256, 0, stream>>>(ei0, ei1, ei2, cnt);
    scan1_kernel<<<nscan, 1024, 0, stream>>>(cnt, offs, bsum);
    scan2_kernel<<<1, 64, 0, stream>>>(bsum, offs, nscan);
    scan3_kernel<<<nscan, 1024, 0, stream>>>(offs, bsum, cursor);
    fill_kernel<<<dim3(3125, 3), 256, 0, stream>>>(ei0, ei1, ei2, ew, dinv, cursor, edges);

    // layer 0: hpre = x@W0^T ; hbuf = relu(gather + 3*b0) ; hpre = relu(bn(hbuf))
    gemm_rows_kernel<<<782, 256, 0, stream>>>(x, W0b, hpre, N_NODES);
    gather_spmm_kernel<<<12500, 256, 0, stream>>>(hpre, offs, edges, b0, hbuf);
    stats_kernel<<<512, 256, 0, stream>>>(hbuf, sums0);
    finalize_stats_kernel<<<1, 128, 0, stream>>>(sums0, mu0, rs0);
    bn_apply_kernel<<<512, 256, 0, stream>>>(hbuf, mu0, rs0, g0, be0, nullptr, hpre, 0);

    // layer 1: hbuf = hpre@W1^T ; hpre = relu(gather + 3*b1) ; out = bn(hpre) + x
    gemm_rows_kernel<<<782, 256, 0, stream>>>(hpre, W1b, hbuf, N_NODES);
    gather_spmm_kernel<<<12500, 256, 0, stream>>>(hbuf, offs, edges, b1, hpre);
    stats_kernel<<<512, 256, 0, stream>>>(hpre, sums1);
    finalize_stats_kernel<<<1, 128, 0, stream>>>(sums1, mu1, rs1);
    bn_apply_kernel<<<512, 256, 0, stream>>>(hpre, mu1, rs1, g1, be1, x, out, 1);
}

// Round 3
// 1060.574 us; speedup vs baseline: 8.5714x; 1.5274x over previous
//
#include <hip/hip_runtime.h>
#include <hip/hip_bf16.h>
#include <cstdint>
#include <cstddef>

#define N_NODES 50000
#define F_DIM   128
#define E_EDGES 800000
#define NNZ     (3 * E_EDGES)
#define BN_EPS  1e-5f

typedef __attribute__((ext_vector_type(8))) short short8;
typedef __attribute__((ext_vector_type(4))) float f32x4;
typedef unsigned short ushort_t;

__device__ __forceinline__ ushort_t f2b(float f) {
    union { float f; uint32_t u; } v; v.f = f;
    uint32_t u = v.u + 0x7fffu + ((v.u >> 16) & 1u);  // round-to-nearest-even
    return (ushort_t)(u >> 16);
}
__device__ __forceinline__ float b2f_lo(uint32_t u) { union { uint32_t u; float f; } v; v.u = u << 16; return v.f; }
__device__ __forceinline__ float b2f_hi(uint32_t u) { union { uint32_t u; float f; } v; v.u = u & 0xffff0000u; return v.f; }
__device__ __forceinline__ uint32_t pk2b(float lo, float hi) {
    return ((uint32_t)f2b(hi) << 16) | (uint32_t)f2b(lo);
}

// ---------------------------------------------------------------- prep: f32 -> bf16 weights
__global__ __launch_bounds__(256) void prep_kernel(
    const float* __restrict__ Wa1, const float* __restrict__ W0, const float* __restrict__ W1,
    ushort_t* __restrict__ Wa1b, ushort_t* __restrict__ W0b, ushort_t* __restrict__ W1b)
{
    int i = blockIdx.x * 256 + threadIdx.x;
    if (i < 3 * 16384) Wa1b[i] = f2b(Wa1[i]);
    if (i < 16384) { W0b[i] = f2b(W0[i]); W1b[i] = f2b(W1[i]); }
}

// ---------------------------------------------------------------- x (f32) -> xb (bf16)
__global__ __launch_bounds__(256) void x2b_kernel(const float* __restrict__ x, ushort_t* __restrict__ xb)
{
    int i = blockIdx.x * 256 + threadIdx.x;   // over float4 groups: 6.4M/4 = 1.6M
    if (i >= N_NODES * 32) return;
    float4 v = ((const float4*)x)[i];
    ushort4 o;
    o.x = f2b(v.x); o.y = f2b(v.y); o.z = f2b(v.z); o.w = f2b(v.w);
    ((ushort4*)xb)[i] = o;
}

// ---------------------------------------------------------------- edge MLP -> sigmoid weight + deg
// wave: 32 edges = two 16-edge MFMA tiles sharing B fragments. bf16 x rows (256 B each).
__global__ __launch_bounds__(256) void edge_mlp_kernel(
    const ushort_t* __restrict__ xb,
    const int* __restrict__ ei0, const int* __restrict__ ei1, const int* __restrict__ ei2,
    const ushort_t* __restrict__ Wa1b, const float* __restrict__ ba1,
    const float* __restrict__ Wa2, const float* __restrict__ ba2,
    float* __restrict__ ew, float* __restrict__ deg)
{
    const int s = blockIdx.y;
    const int* ei = (s == 0) ? ei0 : ((s == 1) ? ei1 : ei2);
    const ushort_t* W = Wa1b + s * 16384;
    const float* b1v = ba1 + s * 128;
    const float* w2v = Wa2 + s * 128;
    const float b2 = ba2[s];
    float* ews  = ew  + (size_t)s * E_EDGES;
    float* degs = deg + (size_t)s * N_NODES;

    const int wave = threadIdx.x >> 6;
    const int lane = threadIdx.x & 63;
    const int quad = lane >> 4;
    const int lcol = lane & 15;
    const int e_base = (blockIdx.x * 4 + wave) * 32;
    if (e_base >= E_EDGES) return;

    int rn[2], cn[2];
#pragma unroll
    for (int t = 0; t < 2; t++) {
        const int e = e_base + t * 16 + lcol;
        rn[t] = ei[e];
        cn[t] = ei[E_EDGES + e];
    }

    // A fragments: |x_r - x_c| in bf16; element j of a[t][kb] = row (tile t, lcol), k = kb*32+quad*8+j
    short8 a[2][4];
#pragma unroll
    for (int t = 0; t < 2; t++) {
        const ushort_t* xr = xb + (size_t)rn[t] * 128;
        const ushort_t* xc = xb + (size_t)cn[t] * 128;
#pragma unroll
        for (int kb = 0; kb < 4; kb++) {
            const int k0 = kb * 32 + quad * 8;
            short8 r = *(const short8*)(xr + k0);
            short8 c = *(const short8*)(xc + k0);
            uint32_t* ru = (uint32_t*)&r;
            uint32_t* cu = (uint32_t*)&c;
            short8 d;
            uint32_t* du = (uint32_t*)&d;
#pragma unroll
            for (int j = 0; j < 4; j++) {
                float dlo = fabsf(b2f_lo(ru[j]) - b2f_lo(cu[j]));
                float dhi = fabsf(b2f_hi(ru[j]) - b2f_hi(cu[j]));
                du[j] = pk2b(dlo, dhi);
            }
            a[t][kb] = d;
        }
    }

    float acc[2][4] = {{0.f,0.f,0.f,0.f},{0.f,0.f,0.f,0.f}};
#pragma unroll
    for (int nb = 0; nb < 8; nb++) {
        const int h = nb * 16 + lcol;
        const ushort_t* wp = W + h * 128 + quad * 8;
        short8 b[4];
#pragma unroll
        for (int kb = 0; kb < 4; kb++) b[kb] = *(const short8*)(wp + kb * 32);
        const float bias = b1v[h];
        const float wv = w2v[h];
#pragma unroll
        for (int t = 0; t < 2; t++) {
            f32x4 d = {0.f, 0.f, 0.f, 0.f};
#pragma unroll
            for (int kb = 0; kb < 4; kb++)
                d = __builtin_amdgcn_mfma_f32_16x16x32_bf16(a[t][kb], b[kb], d, 0, 0, 0);
#pragma unroll
            for (int r = 0; r < 4; r++) {
                float v = d[r] + bias;
                v = v > 0.f ? v : 0.f;
                acc[t][r] += v * wv;
            }
        }
    }
    // reduce each acc across the 16 lanes of the quad (xor masks < 16 stay in-quad)
#pragma unroll
    for (int t = 0; t < 2; t++) {
#pragma unroll
        for (int r = 0; r < 4; r++) {
#pragma unroll
            for (int m = 1; m < 16; m <<= 1) acc[t][r] += __shfl_xor(acc[t][r], m, 64);
        }
        if (lcol < 4) {
            float sv = (lcol == 0) ? acc[t][0] : ((lcol == 1) ? acc[t][1] : ((lcol == 2) ? acc[t][2] : acc[t][3]));
            float w = 1.f / (1.f + __expf(-(sv + b2)));
            const int ee = e_base + t * 16 + quad * 4 + lcol;
            ews[ee] = w;
            const int cc = ei[E_EDGES + ee];
            unsafeAtomicAdd(&degs[cc], w);
        }
    }
}

// ---------------------------------------------------------------- dinv
__global__ __launch_bounds__(256) void dinv_kernel(const float* __restrict__ deg,
                                                   float* __restrict__ dinv, int n)
{
    int i = blockIdx.x * 256 + threadIdx.x;
    if (i < n) {
        float d = deg[i];
        dinv[i] = d > 0.f ? rsqrtf(fmaxf(d, 1e-30f)) : 0.f;
    }
}

// ---------------------------------------------------------------- CSR build
__global__ __launch_bounds__(256) void hist_kernel(
    const int* __restrict__ ei0, const int* __restrict__ ei1, const int* __restrict__ ei2,
    int* __restrict__ cnt)
{
    const int s = blockIdx.y;
    const int* ei = (s == 0) ? ei0 : ((s == 1) ? ei1 : ei2);
    int e = blockIdx.x * 256 + threadIdx.x;
    if (e < E_EDGES) atomicAdd(&cnt[ei[E_EDGES + e]], 1);
}

__global__ __launch_bounds__(1024) void scan1_kernel(
    const int* __restrict__ cnt, int* __restrict__ offs, int* __restrict__ bsum)
{
    __shared__ int ls[1024];
    const int tid = threadIdx.x;
    const int i = blockIdx.x * 1024 + tid;
    int v = (i < N_NODES) ? cnt[i] : 0;
    ls[tid] = v;
    __syncthreads();
#pragma unroll
    for (int d = 1; d < 1024; d <<= 1) {
        int t = (tid >= d) ? ls[tid - d] : 0;
        __syncthreads();
        ls[tid] += t;
        __syncthreads();
    }
    int incl = ls[tid];
    if (i < N_NODES) offs[i] = incl - v;
    if (tid == 1023) bsum[blockIdx.x] = incl;
}

__global__ void scan2_kernel(int* __restrict__ bsum, int* __restrict__ offs, int nb)
{
    if (threadIdx.x == 0) {
        int run = 0;
        for (int b = 0; b < nb; b++) { int t = bsum[b]; bsum[b] = run; run += t; }
        offs[N_NODES] = run;
    }
}

__global__ __launch_bounds__(1024) void scan3_kernel(
    int* __restrict__ offs, const int* __restrict__ bsum, int* __restrict__ cursor)
{
    const int i = blockIdx.x * 1024 + threadIdx.x;
    if (i < N_NODES) {
        int o = offs[i] + bsum[blockIdx.x];
        offs[i] = o;
        cursor[i] = o;
    }
}

__global__ __launch_bounds__(256) void fill_kernel(
    const int* __restrict__ ei0, const int* __restrict__ ei1, const int* __restrict__ ei2,
    const float* __restrict__ ew, const float* __restrict__ dinv,
    int* __restrict__ cursor, int2* __restrict__ edges)
{
    const int s = blockIdx.y;
    const int* ei = (s == 0) ? ei0 : ((s == 1) ? ei1 : ei2);
    const float* ews = ew + (size_t)s * E_EDGES;
    const float* ds  = dinv + (size_t)s * N_NODES;
    int e = blockIdx.x * 256 + threadIdx.x;
    if (e >= E_EDGES) return;
    const int rn = ei[e];
    const int cn = ei[E_EDGES + e];
    const float w = ds[rn] * ews[e] * ds[cn];
    int pos = atomicAdd(&cursor[cn], 1);
    edges[pos] = make_int2(rn, __float_as_int(w));
}

// ---------------------------------------------------------------- gather-SpMM (bf16 rows):
// vout_b[n] = bf16(relu(sum_e w_e * hb[src_e] + 3*bias)); one wave per node, lane owns features 2l,2l+1
__global__ __launch_bounds__(256) void gather_spmm_kernel(
    const ushort_t* __restrict__ hb, const int* __restrict__ offs,
    const int2* __restrict__ edges, const float* __restrict__ bias,
    ushort_t* __restrict__ vb)
{
    const int wave = threadIdx.x >> 6;
    const int lane = threadIdx.x & 63;
    const int node = blockIdx.x * 4 + wave;
    if (node >= N_NODES) return;
    const int start = offs[node];
    const int end   = offs[node + 1];
    const int f = lane * 2;

    float ax = 0.f, ay = 0.f;
    int e = start;
    for (; e + 4 <= end; e += 4) {
        int2 ev0 = edges[e], ev1 = edges[e + 1], ev2 = edges[e + 2], ev3 = edges[e + 3];
        uint32_t u0 = *(const uint32_t*)(hb + (size_t)ev0.x * 128 + f);
        uint32_t u1 = *(const uint32_t*)(hb + (size_t)ev1.x * 128 + f);
        uint32_t u2 = *(const uint32_t*)(hb + (size_t)ev2.x * 128 + f);
        uint32_t u3 = *(const uint32_t*)(hb + (size_t)ev3.x * 128 + f);
        float w0 = __int_as_float(ev0.y), w1 = __int_as_float(ev1.y);
        float w2 = __int_as_float(ev2.y), w3 = __int_as_float(ev3.y);
        ax += w0 * b2f_lo(u0); ay += w0 * b2f_hi(u0);
        ax += w1 * b2f_lo(u1); ay += w1 * b2f_hi(u1);
        ax += w2 * b2f_lo(u2); ay += w2 * b2f_hi(u2);
        ax += w3 * b2f_lo(u3); ay += w3 * b2f_hi(u3);
    }
    for (; e < end; e++) {
        int2 ev = edges[e];
        uint32_t u = *(const uint32_t*)(hb + (size_t)ev.x * 128 + f);
        float w = __int_as_float(ev.y);
        ax += w * b2f_lo(u); ay += w * b2f_hi(u);
    }
    ax += 3.f * bias[f];     ax = ax > 0.f ? ax : 0.f;
    ay += 3.f * bias[f + 1]; ay = ay > 0.f ? ay : 0.f;
    *(uint32_t*)(vb + (size_t)node * 128 + f) = pk2b(ax, ay);
}

// ---------------------------------------------------------------- dense GEMM, bf16 in/out: hb[i][h] = Ab[i][:]·W[h][:]
__global__ __launch_bounds__(256) void gemm_rows_kernel(
    const ushort_t* __restrict__ Ab, const ushort_t* __restrict__ Wb,
    ushort_t* __restrict__ outb, int n)
{
    const int wave = threadIdx.x >> 6;
    const int lane = threadIdx.x & 63;
    const int quad = lane >> 4;
    const int lcol = lane & 15;
    const int i0 = (blockIdx.x * 4 + wave) * 16;
    if (i0 >= n) return;

    short8 a[4];
    const ushort_t* ar = Ab + (size_t)(i0 + lcol) * 128;
#pragma unroll
    for (int kb = 0; kb < 4; kb++) a[kb] = *(const short8*)(ar + kb * 32 + quad * 8);

#pragma unroll
    for (int nb = 0; nb < 8; nb++) {
        f32x4 d = {0.f, 0.f, 0.f, 0.f};
        const ushort_t* wp = Wb + (nb * 16 + lcol) * 128 + quad * 8;
#pragma unroll
        for (int kb = 0; kb < 4; kb++) {
            short8 b = *(const short8*)(wp + kb * 32);
            d = __builtin_amdgcn_mfma_f32_16x16x32_bf16(a[kb], b, d, 0, 0, 0);
        }
#pragma unroll
        for (int r = 0; r < 4; r++) {
            outb[(size_t)(i0 + quad * 4 + r) * 128 + nb * 16 + lcol] = f2b(d[r]);
        }
    }
}

// ---------------------------------------------------------------- per-feature sum/sumsq of bf16 v (already relu'd)
// thread t always sees feature pair p = t & 63 (stride is a multiple of 64 uints)
__global__ __launch_bounds__(256) void stats_kernel(
    const ushort_t* __restrict__ vb, float* __restrict__ sums)
{
    __shared__ float lsx[256], lsy[256], l2x[256], l2y[256];
    float sx = 0.f, sy = 0.f, s2x = 0.f, s2y = 0.f;
    const uint32_t* vu = (const uint32_t*)vb;
    const long total = (long)N_NODES * 64;
    const long stride = (long)gridDim.x * 256;
    for (long i = (long)blockIdx.x * 256 + threadIdx.x; i < total; i += stride) {
        uint32_t u = vu[i];
        float lo = b2f_lo(u), hi = b2f_hi(u);
        sx += lo; sy += hi; s2x += lo * lo; s2y += hi * hi;
    }
    lsx[threadIdx.x] = sx; lsy[threadIdx.x] = sy;
    l2x[threadIdx.x] = s2x; l2y[threadIdx.x] = s2y;
    __syncthreads();
    if (threadIdx.x < 64) {
        const int t = threadIdx.x;
        sx  = lsx[t] + lsx[t + 64] + lsx[t + 128] + lsx[t + 192];
        sy  = lsy[t] + lsy[t + 64] + lsy[t + 128] + lsy[t + 192];
        s2x = l2x[t] + l2x[t + 64] + l2x[t + 128] + l2x[t + 192];
        s2y = l2y[t] + l2y[t + 64] + l2y[t + 128] + l2y[t + 192];
        const int f = t * 2;
        unsafeAtomicAdd(&sums[f], sx);
        unsafeAtomicAdd(&sums[f + 1], sy);
        unsafeAtomicAdd(&sums[128 + f], s2x);
        unsafeAtomicAdd(&sums[128 + f + 1], s2y);
    }
}

__global__ void finalize_stats_kernel(const float* __restrict__ sums,
                                      float* __restrict__ mu, float* __restrict__ rstd)
{
    int f = threadIdx.x;
    float m = sums[f] / (float)N_NODES;
    float var = sums[128 + f] / (float)N_NODES - m * m;
    mu[f] = m;
    rstd[f] = rsqrtf(var + BN_EPS);
}

// ---------------------------------------------------------------- mode 0: outb = bf16(relu(bn(v)));  mode 1: outf = bn(v) + xres
__global__ __launch_bounds__(256) void bn_apply_kernel(
    const ushort_t* __restrict__ vb, const float* __restrict__ mu, const float* __restrict__ rstd,
    const float* __restrict__ gamma, const float* __restrict__ beta,
    const float* __restrict__ xres, ushort_t* __restrict__ outb, float* __restrict__ outf, int mode)
{
    const uint32_t* vu = (const uint32_t*)vb;
    const long total = (long)N_NODES * 64;
    const long stride = (long)gridDim.x * 256;
    for (long i = (long)blockIdx.x * 256 + threadIdx.x; i < total; i += stride) {
        const int f = ((int)(i & 63)) * 2;
        uint32_t u = vu[i];
        float lo = (b2f_lo(u) - mu[f]) * rstd[f] * gamma[f] + beta[f];
        float hi = (b2f_hi(u) - mu[f + 1]) * rstd[f + 1] * gamma[f + 1] + beta[f + 1];
        if (mode == 0) {
            lo = lo > 0.f ? lo : 0.f;
            hi = hi > 0.f ? hi : 0.f;
            ((uint32_t*)outb)[i] = pk2b(lo, hi);
        } else {
            float2 xr = ((const float2*)xres)[i];
            ((float2*)outf)[i] = make_float2(lo + xr.x, hi + xr.y);
        }
    }
}

// ----------------------------------------------------------------
extern "C" void kernel_launch(void* const* d_in, const int* in_sizes, int n_in,
                              void* d_out, int out_size, void* d_ws, size_t ws_size,
                              hipStream_t stream)
{
    const float* x   = (const float*)d_in[0];
    const int* ei0   = (const int*)d_in[1];
    const int* ei1   = (const int*)d_in[2];
    const int* ei2   = (const int*)d_in[3];
    const float* Wa1 = (const float*)d_in[4];
    const float* ba1 = (const float*)d_in[5];
    const float* Wa2 = (const float*)d_in[6];
    const float* ba2 = (const float*)d_in[7];
    const float* W0  = (const float*)d_in[8];
    const float* b0  = (const float*)d_in[9];
    const float* W1  = (const float*)d_in[10];
    const float* b1  = (const float*)d_in[11];
    const float* g0  = (const float*)d_in[12];
    const float* be0 = (const float*)d_in[13];
    const float* g1  = (const float*)d_in[14];
    const float* be1 = (const float*)d_in[15];
    float* out = (float*)d_out;

    char* ws = (char*)d_ws;
    size_t off = 0;
    auto alloc = [&](size_t bytes) -> void* {
        void* p = ws + off;
        off += (bytes + 255) & ~(size_t)255;
        return p;
    };
    ushort_t* Wa1b = (ushort_t*)alloc(3 * 16384 * 2);
    ushort_t* W0b  = (ushort_t*)alloc(16384 * 2);
    ushort_t* W1b  = (ushort_t*)alloc(16384 * 2);
    float* ew    = (float*)alloc(3ull * E_EDGES * 4);
    float* deg   = (float*)alloc(3ull * N_NODES * 4);
    float* dinv  = (float*)alloc(3ull * N_NODES * 4);
    int*   cnt   = (int*)alloc((size_t)N_NODES * 4);
    int*   offs  = (int*)alloc(((size_t)N_NODES + 1) * 4);
    int*   cursor= (int*)alloc((size_t)N_NODES * 4);
    int*   bsum  = (int*)alloc(64 * 4);
    int2*  edges = (int2*)alloc((size_t)NNZ * 8);
    ushort_t* xb  = (ushort_t*)alloc((size_t)N_NODES * 128 * 2);
    ushort_t* hb  = (ushort_t*)alloc((size_t)N_NODES * 128 * 2);  // gemm out (both layers)
    ushort_t* vbb = (ushort_t*)alloc((size_t)N_NODES * 128 * 2);  // gather out (both layers)
    ushort_t* hpb = (ushort_t*)alloc((size_t)N_NODES * 128 * 2);  // bn0 out
    float* sums0 = (float*)alloc(256 * 4);
    float* sums1 = (float*)alloc(256 * 4);
    float* mu0 = (float*)alloc(128 * 4);
    float* rs0 = (float*)alloc(128 * 4);
    float* mu1 = (float*)alloc(128 * 4);
    float* rs1 = (float*)alloc(128 * 4);
    (void)ws_size; (void)in_sizes; (void)n_in; (void)out_size;

    hipMemsetAsync(deg, 0, 3ull * N_NODES * 4, stream);
    hipMemsetAsync(cnt, 0, (size_t)N_NODES * 4, stream);
    hipMemsetAsync(sums0, 0, 256 * 4, stream);
    hipMemsetAsync(sums1, 0, 256 * 4, stream);

    prep_kernel<<<192, 256, 0, stream>>>(Wa1, W0, W1, Wa1b, W0b, W1b);
    x2b_kernel<<<6250, 256, 0, stream>>>(x, xb);

    // edge weights + degrees (32 edges per wave)
    edge_mlp_kernel<<<dim3(6250, 3), 256, 0, stream>>>(xb, ei0, ei1, ei2, Wa1b, ba1, Wa2, ba2, ew, deg);
    dinv_kernel<<<(3 * N_NODES + 255) / 256, 256, 0, stream>>>(deg, dinv, 3 * N_NODES);

    // combined CSR (by destination), reused by both layers
    const int nscan = (N_NODES + 1023) / 1024;  // 49
    hist_kernel<<<dim3(3125, 3), 256, 0, stream>>>(ei0, ei1, ei2, cnt);
    scan1_kernel<<<nscan, 1024, 0, stream>>>(cnt, offs, bsum);
    scan2_kernel<<<1, 64, 0, stream>>>(bsum, offs, nscan);
    scan3_kernel<<<nscan, 1024, 0, stream>>>(offs, bsum, cursor);
    fill_kernel<<<dim3(3125, 3), 256, 0, stream>>>(ei0, ei1, ei2, ew, dinv, cursor, edges);

    // layer 0
    gemm_rows_kernel<<<782, 256, 0, stream>>>(xb, W0b, hb, N_NODES);
    gather_spmm_kernel<<<12500, 256, 0, stream>>>(hb, offs, edges, b0, vbb);
    stats_kernel<<<512, 256, 0, stream>>>(vbb, sums0);
    finalize_stats_kernel<<<1, 128, 0, stream>>>(sums0, mu0, rs0);
    bn_apply_kernel<<<512, 256, 0, stream>>>(vbb, mu0, rs0, g0, be0, nullptr, hpb, nullptr, 0);

    // layer 1
    gemm_rows_kernel<<<782, 256, 0, stream>>>(hpb, W1b, hb, N_NODES);
    gather_spmm_kernel<<<12500, 256, 0, stream>>>(hb, offs, edges, b1, vbb);
    stats_kernel<<<512, 256, 0, stream>>>(vbb, sums1);
    finalize_stats_kernel<<<1, 128, 0, stream>>>(sums1, mu1, rs1);
    bn_apply_kernel<<<512, 256, 0, stream>>>(vbb, mu1, rs1, g1, be1, x, nullptr, out, 1);
}